// Round 4
// baseline (767.387 us; speedup 1.0000x reference)
//
#include <hip/hip_runtime.h>
#include <math.h>

// ---- problem constants ----
#define OUT_XT     0
#define OUT_GRID   33554432
#define OUT_REG    58720256
#define OUT_MOVED  58720264
#define FC1_K      576000

// scratch inside d_out (regions consumed before being overwritten):
#define WS_BUF1    0          // (8,8,125,125,16) -- inside X_t region
#define WS_BUF2    16000000   // (8,10,60,60,16)
#define WS_PART    20608000   // 1024 x 256
#define WS_RT      58720256   // 8x4x12 -- reg+moved region, overwritten by k_tail

// ======== prep: transpose weights into [ic][dd][oc] for contiguous uniform (s_load) reads ========
__global__ __launch_bounds__(256) void k_prep(const float* __restrict__ w1,
                                              const float* __restrict__ w2,
                                              float* __restrict__ wt1,
                                              float* __restrict__ wt2) {
  const int tid = threadIdx.x;
  for (int t = tid; t < 1568; t += 256) {       // wt1[(ic*49+dd)*8+oc] = w1[(oc*4+ic)*49+dd]
    int oc = t & 7, idx = t >> 3;
    int ic = idx / 49, dd = idx % 49;
    wt1[t] = w1[(oc * 4 + ic) * 49 + dd];
  }
  for (int t = tid; t < 2000; t += 256) {       // wt2[(ic*25+dd)*10+oc] = w2[(oc*8+ic)*25+dd]
    int oc = t % 10, idx = t / 10;
    int ic = idx / 25, dd = idx % 25;
    wt2[t] = w2[(oc * 8 + ic) * 25 + dd];
  }
}

// ================= conv1 (7x7x1, 4->8) + pool(2,2,1) + relu =================
// LDS sIn[k][row][col]: row-stride 16, plane-stride 226 (== 2 mod 32).
// Wave lanes (k=lane&15, pxl=(lane>>4)&3) read b64 at bank 2k+2pxl+cc -> exactly 4 dwords
// per bank = wave64-b64 minimum; zero conflict cycles.
// Rows rotate across dy: row dy+1 loaded fresh, row dy reused from previous iter.
#define C1_RS 16
#define C1_PS 226
__global__ __launch_bounds__(256) void k_conv1(const float* __restrict__ x,
                                               const float* __restrict__ wt1,
                                               const float* __restrict__ b1,
                                               float* __restrict__ buf1) {
  __shared__ float sIn[16 * C1_PS];
  const int tid = threadIdx.x;
  const int tx = blockIdx.x, ty = blockIdx.y, b = blockIdx.z;

  const int k = tid & 15;
  const int pix = tid >> 4;
  const int pyl = pix >> 2, pxl = pix & 3;
  const int row0 = ty * 8, col0 = tx * 8;

  float acc[2][2][8];
#pragma unroll
  for (int a = 0; a < 2; ++a)
#pragma unroll
    for (int c = 0; c < 2; ++c)
#pragma unroll
      for (int oc = 0; oc < 8; ++oc) acc[a][c][oc] = 0.f;

  const float4* __restrict__ x4 = reinterpret_cast<const float4*>(x);
#pragma unroll 1
  for (int ic = 0; ic < 4; ++ic) {
    __syncthreads();
    for (int t = tid; t < 784; t += 256) {
      int q = t & 3, pos = t >> 2;
      int coli = pos % 14, rowi = pos / 14;
      int row = row0 + rowi, col = col0 + coli;
      float4 v = make_float4(0.f, 0.f, 0.f, 0.f);
      if (row < 256 && col < 256)
        v = x4[(((b * 4 + ic) * 256 + row) * 256 + col) * 4 + q];
      int base = rowi * C1_RS + coli;
      sIn[(4 * q + 0) * C1_PS + base] = v.x;
      sIn[(4 * q + 1) * C1_PS + base] = v.y;
      sIn[(4 * q + 2) * C1_PS + base] = v.z;
      sIn[(4 * q + 3) * C1_PS + base] = v.w;
    }
    __syncthreads();

    const int rbase = k * C1_PS + 2 * pxl;
    float ra[8], rb[8];
    // preload row 2pyl+0 into ra
#pragma unroll
    for (int j = 0; j < 4; ++j) {
      float2 f = *reinterpret_cast<const float2*>(&sIn[rbase + (2 * pyl) * C1_RS + 2 * j]);
      ra[2 * j] = f.x; ra[2 * j + 1] = f.y;
    }
#pragma unroll
    for (int dy = 0; dy < 7; ++dy) {
      float* lo = (dy & 1) ? rb : ra;   // row 2pyl+dy (already loaded)
      float* hi = (dy & 1) ? ra : rb;   // row 2pyl+dy+1 (load fresh)
#pragma unroll
      for (int j = 0; j < 4; ++j) {
        float2 f = *reinterpret_cast<const float2*>(&sIn[rbase + (2 * pyl + dy + 1) * C1_RS + 2 * j]);
        hi[2 * j] = f.x; hi[2 * j + 1] = f.y;
      }
      const float* __restrict__ wd = wt1 + ic * 392 + dy * 56;   // uniform -> s_load
#pragma unroll
      for (int dx = 0; dx < 7; ++dx) {
#pragma unroll
        for (int c = 0; c < 2; ++c) {
          const float v0 = lo[c + dx];
          const float v1 = hi[c + dx];
#pragma unroll
          for (int oc = 0; oc < 8; ++oc) {
            acc[0][c][oc] = fmaf(v0, wd[dx * 8 + oc], acc[0][c][oc]);
            acc[1][c][oc] = fmaf(v1, wd[dx * 8 + oc], acc[1][c][oc]);
          }
        }
      }
    }
  }
  const int py = ty * 4 + pyl, px = tx * 4 + pxl;
  if (py < 125 && px < 125) {
#pragma unroll
    for (int oc = 0; oc < 8; ++oc) {
      float m = fmaxf(fmaxf(acc[0][0][oc], acc[0][1][oc]),
                      fmaxf(acc[1][0][oc], acc[1][1][oc])) + b1[oc];
      buf1[(((b * 8 + oc) * 125 + py) * 125 + px) * 16 + k] = fmaxf(m, 0.f);
    }
  }
}

// ================= conv2 (5x5x1, 8->10) + pool + relu =================
#define C2_RS 16
#define C2_PS 194
__global__ __launch_bounds__(256) void k_conv2(const float* __restrict__ in,
                                               const float* __restrict__ wt2,
                                               const float* __restrict__ b2,
                                               float* __restrict__ buf2) {
  __shared__ float sIn[16 * C2_PS];
  const int tid = threadIdx.x;
  const int tx = blockIdx.x, ty = blockIdx.y, b = blockIdx.z;

  const int k = tid & 15;
  const int pix = tid >> 4;
  const int pyl = pix >> 2, pxl = pix & 3;
  const int row0 = ty * 8, col0 = tx * 8;

  float acc[2][2][10];
#pragma unroll
  for (int a = 0; a < 2; ++a)
#pragma unroll
    for (int c = 0; c < 2; ++c)
#pragma unroll
      for (int oc = 0; oc < 10; ++oc) acc[a][c][oc] = 0.f;

  const float4* __restrict__ in4 = reinterpret_cast<const float4*>(in);
#pragma unroll 1
  for (int ic = 0; ic < 8; ++ic) {
    __syncthreads();
    for (int t = tid; t < 576; t += 256) {
      int q = t & 3, pos = t >> 2;
      int coli = pos % 12, rowi = pos / 12;
      int row = row0 + rowi, col = col0 + coli;
      float4 v = in4[(((b * 8 + ic) * 125 + row) * 125 + col) * 4 + q];
      int base = rowi * C2_RS + coli;
      sIn[(4 * q + 0) * C2_PS + base] = v.x;
      sIn[(4 * q + 1) * C2_PS + base] = v.y;
      sIn[(4 * q + 2) * C2_PS + base] = v.z;
      sIn[(4 * q + 3) * C2_PS + base] = v.w;
    }
    __syncthreads();

    const int rbase = k * C2_PS + 2 * pxl;
    float ra[6], rb[6];
#pragma unroll
    for (int j = 0; j < 3; ++j) {
      float2 f = *reinterpret_cast<const float2*>(&sIn[rbase + (2 * pyl) * C2_RS + 2 * j]);
      ra[2 * j] = f.x; ra[2 * j + 1] = f.y;
    }
#pragma unroll
    for (int dy = 0; dy < 5; ++dy) {
      float* lo = (dy & 1) ? rb : ra;
      float* hi = (dy & 1) ? ra : rb;
#pragma unroll
      for (int j = 0; j < 3; ++j) {
        float2 f = *reinterpret_cast<const float2*>(&sIn[rbase + (2 * pyl + dy + 1) * C2_RS + 2 * j]);
        hi[2 * j] = f.x; hi[2 * j + 1] = f.y;
      }
      const float* __restrict__ wd = wt2 + ic * 250 + dy * 50;   // uniform -> s_load
#pragma unroll
      for (int dx = 0; dx < 5; ++dx) {
#pragma unroll
        for (int c = 0; c < 2; ++c) {
          const float v0 = lo[c + dx];
          const float v1 = hi[c + dx];
#pragma unroll
          for (int oc = 0; oc < 10; ++oc) {
            acc[0][c][oc] = fmaf(v0, wd[dx * 10 + oc], acc[0][c][oc]);
            acc[1][c][oc] = fmaf(v1, wd[dx * 10 + oc], acc[1][c][oc]);
          }
        }
      }
    }
  }
  const int py = ty * 4 + pyl, px = tx * 4 + pxl;
#pragma unroll
  for (int oc = 0; oc < 10; ++oc) {
    float m = fmaxf(fmaxf(acc[0][0][oc], acc[0][1][oc]),
                    fmaxf(acc[1][0][oc], acc[1][1][oc])) + b2[oc];
    buf2[(((b * 10 + oc) * 60 + py) * 60 + px) * 16 + k] = fmaxf(m, 0.f);
  }
}

// ================= fc1 split-K pass 1: partial[1024][256] =================
__global__ __launch_bounds__(256) void k_fc1(const float* __restrict__ z,
                                             const float* __restrict__ w,
                                             float* __restrict__ partial) {
  const int bid = blockIdx.x, tid = threadIdx.x;
  const int b = tid >> 5, o = tid & 31;
  int k0 = bid * 563;
  int k1 = k0 + 563;
  if (k1 > FC1_K) k1 = FC1_K;
  const float* __restrict__ zp = z + b * FC1_K;
  const float* __restrict__ wp = w + o * FC1_K;
  float a0 = 0.f, a1 = 0.f, a2 = 0.f, a3 = 0.f;
  int kk = k0;
  for (; kk + 4 <= k1; kk += 4) {
    a0 = fmaf(zp[kk], wp[kk], a0);
    a1 = fmaf(zp[kk + 1], wp[kk + 1], a1);
    a2 = fmaf(zp[kk + 2], wp[kk + 2], a2);
    a3 = fmaf(zp[kk + 3], wp[kk + 3], a3);
  }
  for (; kk < k1; ++kk) a0 = fmaf(zp[kk], wp[kk], a0);
  partial[bid * 256 + tid] = (a0 + a1) + (a2 + a3);
}

// ======== head: reduce partials -> fc1 relu -> fc2 tanh -> R, Tv ========
__global__ __launch_bounds__(256) void k_head(const float* __restrict__ partial,
                                              const float* __restrict__ fc1_b,
                                              const float* __restrict__ fc2_w,
                                              const float* __restrict__ fc2_b,
                                              float* __restrict__ RT) {
  __shared__ float sH[256];
  __shared__ float sTh[8][24];
  const int tid = threadIdx.x;
  float s0 = 0.f, s1 = 0.f, s2 = 0.f, s3 = 0.f;
  for (int c = 0; c < 1024; c += 4) {
    s0 += partial[c * 256 + tid];
    s1 += partial[(c + 1) * 256 + tid];
    s2 += partial[(c + 2) * 256 + tid];
    s3 += partial[(c + 3) * 256 + tid];
  }
  const int o = tid & 31;
  sH[tid] = fmaxf(((s0 + s1) + (s2 + s3)) + fc1_b[o], 0.f);
  __syncthreads();
  if (tid < 192) {
    int b = tid / 24, o2 = tid % 24;
    float a = fc2_b[o2];
#pragma unroll
    for (int i = 0; i < 32; ++i) a = fmaf(sH[b * 32 + i], fc2_w[o2 * 32 + i], a);
    sTh[b][o2] = tanhf(a);
  }
  __syncthreads();
  if (tid < 32) {
    const int b = tid >> 2, t = tid & 3;
    const float PI = 3.14159265358979323846f;
    float a0 = PI * sTh[b][t * 6 + 0];
    float a1 = PI * sTh[b][t * 6 + 1];
    float a2 = PI * sTh[b][t * 6 + 2];
    float t0 = sTh[b][t * 6 + 3], t1 = sTh[b][t * 6 + 4], t2 = sTh[b][t * 6 + 5];
    float c0 = cosf(a0), s0v = sinf(a0);
    float c1 = cosf(a1), s1v = sinf(a1);
    float c2 = cosf(a2), s2v = sinf(a2);
    float R[3][3];
    R[0][0] = c0 * c1;
    R[0][1] = c0 * s1v * s2v - s0v * c2;
    R[0][2] = c0 * s1v * c2 + s0v * s2v;
    R[1][0] = s0v * c1;
    R[1][1] = s0v * s1v * s2v + c0 * c2;
    R[1][2] = s0v * s1v * c2 - c0 * s2v;
    R[2][0] = -s1v;
    R[2][1] = c1 * s2v;
    R[2][2] = c1 * c2;
    const float SZv[3] = {256.f, 256.f, 16.f};
    const float cen[3] = {128.f, 128.f, 8.f};
    const float tr[3] = {t0, t1, t2};
    float* rt = RT + (b * 4 + t) * 12;
#pragma unroll
    for (int kq = 0; kq < 3; ++kq)
#pragma unroll
      for (int s = 0; s < 3; ++s) rt[kq * 3 + s] = R[kq][s];
#pragma unroll
    for (int s = 0; s < 3; ++s)
      rt[9 + s] = tr[s] * SZv[s] + cen[s] - (128.f * R[0][s] + 128.f * R[1][s] + 8.f * R[2][s]);
  }
}

// ====== flow + grid_out + trilinear grid-sample -> X_t ======
__global__ __launch_bounds__(256) void k_flow(const float* __restrict__ x,
                                              const float* __restrict__ RT,
                                              float* __restrict__ out) {
  const int bid = blockIdx.x;
  const int b = bid >> 12;
  const int l = ((bid & 4095) << 8) | threadIdx.x;
  const int i = l >> 12, j = (l >> 4) & 255, k = l & 15;
  const float fi = (float)i, fj = (float)j, fk = (float)k;
  const float* __restrict__ rt = RT + b * 48;

  const float txs[4] = {64.f, 64.f, 192.f, 192.f};
  const float tys[4] = {64.f, 192.f, 64.f, 192.f};
  float e[4], es = 0.f;
#pragma unroll
  for (int t = 0; t < 4; ++t) {
    float dx = fi - txs[t], dy = fj - tys[t], dz = fk - 8.f;
    float d = sqrtf(dx * dx + dy * dy + dz * dz);
    e[t] = __expf(-0.1f * d);
    es += e[t];
  }
  float inv = 1.f / es;
  float f0 = 0.f, f1 = 0.f, f2 = 0.f;
#pragma unroll
  for (int t = 0; t < 4; ++t) {
    float wt = e[t] * inv;
    const float* r = rt + t * 12;
    f0 += wt * (fi * r[0] + fj * r[3] + fk * r[6] + r[9]);
    f1 += wt * (fi * r[1] + fj * r[4] + fk * r[7] + r[10]);
    f2 += wt * (fi * r[2] + fj * r[5] + fk * r[8] + r[11]);
  }
  float nf0 = f0 * (1.f / 128.f) - 1.f;
  float nf1 = f1 * (1.f / 128.f) - 1.f;
  float nf2 = f2 * 0.125f - 1.f;

  int gbase = OUT_GRID + ((b << 20) + l) * 3;
  out[gbase] = nf2;
  out[gbase + 1] = nf1;
  out[gbase + 2] = nf0;

  float ix = ((nf2 + 1.f) * 16.f - 1.f) * 0.5f;
  float iy = ((nf1 + 1.f) * 256.f - 1.f) * 0.5f;
  float iz = ((nf0 + 1.f) * 256.f - 1.f) * 0.5f;
  float xf = floorf(ix), yf = floorf(iy), zf = floorf(iz);
  float fx = ix - xf, fy = iy - yf, fz = iz - zf;
  int x0 = (int)xf, y0 = (int)yf, z0 = (int)zf;
  int x1 = x0 + 1, y1 = y0 + 1, z1 = z0 + 1;
  bool vx0 = ((unsigned)x0 < 16u), vx1 = ((unsigned)x1 < 16u);
  bool vy0 = ((unsigned)y0 < 256u), vy1 = ((unsigned)y1 < 256u);
  bool vz0 = ((unsigned)z0 < 256u), vz1 = ((unsigned)z1 < 256u);
  int cx0 = min(max(x0, 0), 15), cx1 = min(max(x1, 0), 15);
  int cy0 = min(max(y0, 0), 255), cy1 = min(max(y1, 0), 255);
  int cz0 = min(max(z0, 0), 255), cz1 = min(max(z1, 0), 255);
  float wx0 = 1.f - fx, wx1 = fx, wy0 = 1.f - fy, wy1 = fy, wz0 = 1.f - fz, wz1 = fz;

  float W000 = wz0 * wy0 * wx0 * ((vz0 && vy0 && vx0) ? 1.f : 0.f);
  float W001 = wz0 * wy0 * wx1 * ((vz0 && vy0 && vx1) ? 1.f : 0.f);
  float W010 = wz0 * wy1 * wx0 * ((vz0 && vy1 && vx0) ? 1.f : 0.f);
  float W011 = wz0 * wy1 * wx1 * ((vz0 && vy1 && vx1) ? 1.f : 0.f);
  float W100 = wz1 * wy0 * wx0 * ((vz1 && vy0 && vx0) ? 1.f : 0.f);
  float W101 = wz1 * wy0 * wx1 * ((vz1 && vy0 && vx1) ? 1.f : 0.f);
  float W110 = wz1 * wy1 * wx0 * ((vz1 && vy1 && vx0) ? 1.f : 0.f);
  float W111 = wz1 * wy1 * wx1 * ((vz1 && vy1 && vx1) ? 1.f : 0.f);

  int o000 = (cz0 << 12) + (cy0 << 4) + cx0;
  int o001 = (cz0 << 12) + (cy0 << 4) + cx1;
  int o010 = (cz0 << 12) + (cy1 << 4) + cx0;
  int o011 = (cz0 << 12) + (cy1 << 4) + cx1;
  int o100 = (cz1 << 12) + (cy0 << 4) + cx0;
  int o101 = (cz1 << 12) + (cy0 << 4) + cx1;
  int o110 = (cz1 << 12) + (cy1 << 4) + cx0;
  int o111 = (cz1 << 12) + (cy1 << 4) + cx1;

#pragma unroll
  for (int c = 0; c < 4; ++c) {
    const float* __restrict__ xb = x + (((b * 4 + c) << 20));
    float v = W000 * xb[o000] + W001 * xb[o001] + W010 * xb[o010] + W011 * xb[o011] +
              W100 * xb[o100] + W101 * xb[o101] + W110 * xb[o110] + W111 * xb[o111];
    out[OUT_XT + ((b * 4 + c) << 20) + l] = v;
  }
}

// ====== moved + reg ======
__global__ __launch_bounds__(256) void k_tail(const float* __restrict__ P,
                                              const float* __restrict__ centers,
                                              const int* __restrict__ times,
                                              float* __restrict__ out) {
  const int b = blockIdx.x, tid = threadIdx.x;
  __shared__ float sred[256];
  float nrm = 0.f;
  if (tid < 200) {
    int tb = times[b];
    float p0 = P[tid * 96 + tb];
    float p1 = P[tid * 96 + 32 + tb];
    float p2 = P[tid * 96 + 64 + tb];
    int i0 = (int)rintf(p0), i1 = (int)rintf(p1), i2 = (int)rintf(p2);
    int lp = (i0 << 12) + (i1 << 4) + i2;
    int gb = OUT_GRID + ((b << 20) + lp) * 3;
    float a0 = out[gb + 2];
    float a1 = out[gb + 1];
    float a2 = out[gb + 0];
    float m0 = 2.f * p0 - (0.5f + 0.5f * a0) * 255.f;
    float m1 = 2.f * p1 - (0.5f + 0.5f * a1) * 255.f;
    float m2 = 2.f * p2 - (0.5f + 0.5f * a2) * 15.f;
    int mo = OUT_MOVED + (b * 200 + tid) * 3;
    out[mo] = m0;
    out[mo + 1] = m1;
    out[mo + 2] = m2;
    float d0 = m0 - centers[tid * 3];
    float d1 = m1 - centers[tid * 3 + 1];
    float d2 = m2 - centers[tid * 3 + 2];
    nrm = sqrtf(d0 * d0 + d1 * d1 + d2 * d2);
  }
  sred[tid] = nrm;
  __syncthreads();
  for (int s = 128; s > 0; s >>= 1) {
    if (tid < s) sred[tid] += sred[tid + s];
    __syncthreads();
  }
  if (tid == 0) out[OUT_REG + b] = sred[0] * 0.005f;
}

extern "C" void kernel_launch(void* const* d_in, const int* in_sizes, int n_in,
                              void* d_out, int out_size, void* d_ws, size_t ws_size,
                              hipStream_t stream) {
  const float* x = (const float*)d_in[0];
  const int* times = (const int*)d_in[1];
  const float* w1 = (const float*)d_in[2];
  const float* b1 = (const float*)d_in[3];
  const float* w2 = (const float*)d_in[4];
  const float* b2 = (const float*)d_in[5];
  const float* fw1 = (const float*)d_in[6];
  const float* fb1 = (const float*)d_in[7];
  const float* fw2 = (const float*)d_in[8];
  const float* fb2 = (const float*)d_in[9];
  const float* P = (const float*)d_in[10];
  const float* centers = (const float*)d_in[11];
  float* out = (float*)d_out;

  float* wt1 = (float*)d_ws;          // 1568 floats
  float* wt2 = wt1 + 1568;            // 2000 floats

  float* buf1 = out + WS_BUF1;
  float* buf2 = out + WS_BUF2;
  float* partial = out + WS_PART;
  float* RT = out + WS_RT;

  k_prep<<<1, 256, 0, stream>>>(w1, w2, wt1, wt2);
  k_conv1<<<dim3(32, 32, 8), 256, 0, stream>>>(x, wt1, b1, buf1);
  k_conv2<<<dim3(15, 15, 8), 256, 0, stream>>>(buf1, wt2, b2, buf2);
  k_fc1<<<1024, 256, 0, stream>>>(buf2, fw1, partial);
  k_head<<<1, 256, 0, stream>>>(partial, fb1, fw2, fb2, RT);
  k_flow<<<32768, 256, 0, stream>>>(x, RT, out);
  k_tail<<<8, 256, 0, stream>>>(P, centers, times, out);
}

// Round 5
// 648.381 us; speedup vs baseline: 1.1835x; 1.1835x over previous
//
#include <hip/hip_runtime.h>
#include <math.h>

// ---- problem constants ----
#define OUT_XT     0
#define OUT_GRID   33554432
#define OUT_REG    58720256
#define OUT_MOVED  58720264
#define FC1_K      576000

// scratch inside d_out (regions consumed before being overwritten):
#define WS_BUF1    0          // (8,8,125,125,16) -- inside X_t region
#define WS_BUF2    16000000   // (8,10,60,60,16)
#define WS_PART    20608000   // 2048 x 256
#define WS_RT      58720256   // 8x4x12 -- reg+moved region, overwritten by k_tail

// ======== prep: transpose weights into [ic][dd][oc] for contiguous uniform (s_load) reads ========
__global__ __launch_bounds__(256) void k_prep(const float* __restrict__ w1,
                                              const float* __restrict__ w2,
                                              float* __restrict__ wt1,
                                              float* __restrict__ wt2) {
  const int tid = threadIdx.x;
  for (int t = tid; t < 1568; t += 256) {       // wt1[(ic*49+dd)*8+oc] = w1[(oc*4+ic)*49+dd]
    int oc = t & 7, idx = t >> 3;
    int ic = idx / 49, dd = idx % 49;
    wt1[t] = w1[(oc * 4 + ic) * 49 + dd];
  }
  for (int t = tid; t < 2000; t += 256) {       // wt2[(ic*25+dd)*10+oc] = w2[(oc*8+ic)*25+dd]
    int oc = t % 10, idx = t / 10;
    int ic = idx / 25, dd = idx % 25;
    wt2[t] = w2[(oc * 8 + ic) * 25 + dd];
  }
}

// ================= conv1 (7x7x1, 4->8) + pool(2,2,1) + relu =================
// R3 structure (dy rolled, both rows loaded per dy -- unrolling dy cost +50% VALU in R4).
// Pad PS == 2 (mod 32): wave b64 reads hit exactly 4 dwords/bank (conflict-free minimum).
#define C1_RS 16
#define C1_PS 226
__global__ __launch_bounds__(256) void k_conv1(const float* __restrict__ x,
                                               const float* __restrict__ wt1,
                                               const float* __restrict__ b1,
                                               float* __restrict__ buf1) {
  __shared__ float sIn[16 * C1_PS];
  const int tid = threadIdx.x;
  const int tx = blockIdx.x, ty = blockIdx.y, b = blockIdx.z;

  const int k = tid & 15;
  const int pix = tid >> 4;
  const int pyl = pix >> 2, pxl = pix & 3;
  const int row0 = ty * 8, col0 = tx * 8;

  float acc[2][2][8];
#pragma unroll
  for (int a = 0; a < 2; ++a)
#pragma unroll
    for (int c = 0; c < 2; ++c)
#pragma unroll
      for (int oc = 0; oc < 8; ++oc) acc[a][c][oc] = 0.f;

  const float4* __restrict__ x4 = reinterpret_cast<const float4*>(x);
#pragma unroll 1
  for (int ic = 0; ic < 4; ++ic) {
    __syncthreads();
    for (int t = tid; t < 784; t += 256) {
      int q = t & 3, pos = t >> 2;
      int coli = pos % 14, rowi = pos / 14;
      int row = row0 + rowi, col = col0 + coli;
      float4 v = make_float4(0.f, 0.f, 0.f, 0.f);
      if (row < 256 && col < 256)
        v = x4[(((b * 4 + ic) * 256 + row) * 256 + col) * 4 + q];
      int base = rowi * C1_RS + coli;
      sIn[(4 * q + 0) * C1_PS + base] = v.x;
      sIn[(4 * q + 1) * C1_PS + base] = v.y;
      sIn[(4 * q + 2) * C1_PS + base] = v.z;
      sIn[(4 * q + 3) * C1_PS + base] = v.w;
    }
    __syncthreads();
#pragma unroll 1
    for (int dy = 0; dy < 7; ++dy) {
      float v[2][8];
#pragma unroll
      for (int a = 0; a < 2; ++a) {
        const int base = k * C1_PS + (2 * pyl + a + dy) * C1_RS + 2 * pxl;
#pragma unroll
        for (int j = 0; j < 4; ++j) {
          float2 f = *reinterpret_cast<const float2*>(&sIn[base + 2 * j]);
          v[a][2 * j] = f.x;
          v[a][2 * j + 1] = f.y;
        }
      }
      const float* __restrict__ wd = wt1 + ic * 392 + dy * 56;   // uniform -> s_load
#pragma unroll
      for (int dx = 0; dx < 7; ++dx) {
#pragma unroll
        for (int a = 0; a < 2; ++a)
#pragma unroll
          for (int c = 0; c < 2; ++c) {
            const float val = v[a][c + dx];
#pragma unroll
            for (int oc = 0; oc < 8; ++oc)
              acc[a][c][oc] = fmaf(val, wd[dx * 8 + oc], acc[a][c][oc]);
          }
      }
    }
  }
  const int py = ty * 4 + pyl, px = tx * 4 + pxl;
  if (py < 125 && px < 125) {
#pragma unroll
    for (int oc = 0; oc < 8; ++oc) {
      float m = fmaxf(fmaxf(acc[0][0][oc], acc[0][1][oc]),
                      fmaxf(acc[1][0][oc], acc[1][1][oc])) + b1[oc];
      buf1[(((b * 8 + oc) * 125 + py) * 125 + px) * 16 + k] = fmaxf(m, 0.f);
    }
  }
}

// ================= conv2 (5x5x1, 8->10) + pool + relu =================
#define C2_RS 16
#define C2_PS 194
__global__ __launch_bounds__(256) void k_conv2(const float* __restrict__ in,
                                               const float* __restrict__ wt2,
                                               const float* __restrict__ b2,
                                               float* __restrict__ buf2) {
  __shared__ float sIn[16 * C2_PS];
  const int tid = threadIdx.x;
  const int tx = blockIdx.x, ty = blockIdx.y, b = blockIdx.z;

  const int k = tid & 15;
  const int pix = tid >> 4;
  const int pyl = pix >> 2, pxl = pix & 3;
  const int row0 = ty * 8, col0 = tx * 8;

  float acc[2][2][10];
#pragma unroll
  for (int a = 0; a < 2; ++a)
#pragma unroll
    for (int c = 0; c < 2; ++c)
#pragma unroll
      for (int oc = 0; oc < 10; ++oc) acc[a][c][oc] = 0.f;

  const float4* __restrict__ in4 = reinterpret_cast<const float4*>(in);
#pragma unroll 1
  for (int ic = 0; ic < 8; ++ic) {
    __syncthreads();
    for (int t = tid; t < 576; t += 256) {
      int q = t & 3, pos = t >> 2;
      int coli = pos % 12, rowi = pos / 12;
      int row = row0 + rowi, col = col0 + coli;
      float4 v = in4[(((b * 8 + ic) * 125 + row) * 125 + col) * 4 + q];
      int base = rowi * C2_RS + coli;
      sIn[(4 * q + 0) * C2_PS + base] = v.x;
      sIn[(4 * q + 1) * C2_PS + base] = v.y;
      sIn[(4 * q + 2) * C2_PS + base] = v.z;
      sIn[(4 * q + 3) * C2_PS + base] = v.w;
    }
    __syncthreads();
#pragma unroll 1
    for (int dy = 0; dy < 5; ++dy) {
      float v[2][6];
#pragma unroll
      for (int a = 0; a < 2; ++a) {
        const int base = k * C2_PS + (2 * pyl + a + dy) * C2_RS + 2 * pxl;
#pragma unroll
        for (int j = 0; j < 3; ++j) {
          float2 f = *reinterpret_cast<const float2*>(&sIn[base + 2 * j]);
          v[a][2 * j] = f.x;
          v[a][2 * j + 1] = f.y;
        }
      }
      const float* __restrict__ wd = wt2 + ic * 250 + dy * 50;   // uniform -> s_load
#pragma unroll
      for (int dx = 0; dx < 5; ++dx) {
#pragma unroll
        for (int a = 0; a < 2; ++a)
#pragma unroll
          for (int c = 0; c < 2; ++c) {
            const float val = v[a][c + dx];
#pragma unroll
            for (int oc = 0; oc < 10; ++oc)
              acc[a][c][oc] = fmaf(val, wd[dx * 10 + oc], acc[a][c][oc]);
          }
      }
    }
  }
  const int py = ty * 4 + pyl, px = tx * 4 + pxl;
#pragma unroll
  for (int oc = 0; oc < 10; ++oc) {
    float m = fmaxf(fmaxf(acc[0][0][oc], acc[0][1][oc]),
                    fmaxf(acc[1][0][oc], acc[1][1][oc])) + b2[oc];
    buf2[(((b * 10 + oc) * 60 + py) * 60 + px) * 16 + k] = fmaxf(m, 0.f);
  }
}

// ================= fc1 split-K pass 1: partial[2048][256] =================
// 2048 blocks (8192 waves) for latency hiding; 8-deep unroll for MLP.
__global__ __launch_bounds__(256) void k_fc1(const float* __restrict__ z,
                                             const float* __restrict__ w,
                                             float* __restrict__ partial) {
  const int bid = blockIdx.x, tid = threadIdx.x;
  const int b = tid >> 5, o = tid & 31;
  int k0 = bid * 282;
  int k1 = k0 + 282;
  if (k1 > FC1_K) k1 = FC1_K;
  const float* __restrict__ zp = z + b * FC1_K;
  const float* __restrict__ wp = w + o * FC1_K;
  float a0 = 0.f, a1 = 0.f, a2 = 0.f, a3 = 0.f;
  float a4 = 0.f, a5 = 0.f, a6 = 0.f, a7 = 0.f;
  int kk = k0;
  for (; kk + 8 <= k1; kk += 8) {
    a0 = fmaf(zp[kk], wp[kk], a0);
    a1 = fmaf(zp[kk + 1], wp[kk + 1], a1);
    a2 = fmaf(zp[kk + 2], wp[kk + 2], a2);
    a3 = fmaf(zp[kk + 3], wp[kk + 3], a3);
    a4 = fmaf(zp[kk + 4], wp[kk + 4], a4);
    a5 = fmaf(zp[kk + 5], wp[kk + 5], a5);
    a6 = fmaf(zp[kk + 6], wp[kk + 6], a6);
    a7 = fmaf(zp[kk + 7], wp[kk + 7], a7);
  }
  for (; kk < k1; ++kk) a0 = fmaf(zp[kk], wp[kk], a0);
  partial[bid * 256 + tid] = ((a0 + a1) + (a2 + a3)) + ((a4 + a5) + (a6 + a7));
}

// ======== head: reduce partials -> fc1 relu -> fc2 tanh -> R, Tv ========
__global__ __launch_bounds__(256) void k_head(const float* __restrict__ partial,
                                              const float* __restrict__ fc1_b,
                                              const float* __restrict__ fc2_w,
                                              const float* __restrict__ fc2_b,
                                              float* __restrict__ RT) {
  __shared__ float sH[256];
  __shared__ float sTh[8][24];
  const int tid = threadIdx.x;
  float s0 = 0.f, s1 = 0.f, s2 = 0.f, s3 = 0.f;
  for (int c = 0; c < 2048; c += 4) {
    s0 += partial[c * 256 + tid];
    s1 += partial[(c + 1) * 256 + tid];
    s2 += partial[(c + 2) * 256 + tid];
    s3 += partial[(c + 3) * 256 + tid];
  }
  const int o = tid & 31;
  sH[tid] = fmaxf(((s0 + s1) + (s2 + s3)) + fc1_b[o], 0.f);
  __syncthreads();
  if (tid < 192) {
    int b = tid / 24, o2 = tid % 24;
    float a = fc2_b[o2];
#pragma unroll
    for (int i = 0; i < 32; ++i) a = fmaf(sH[b * 32 + i], fc2_w[o2 * 32 + i], a);
    sTh[b][o2] = tanhf(a);
  }
  __syncthreads();
  if (tid < 32) {
    const int b = tid >> 2, t = tid & 3;
    const float PI = 3.14159265358979323846f;
    float a0 = PI * sTh[b][t * 6 + 0];
    float a1 = PI * sTh[b][t * 6 + 1];
    float a2 = PI * sTh[b][t * 6 + 2];
    float t0 = sTh[b][t * 6 + 3], t1 = sTh[b][t * 6 + 4], t2 = sTh[b][t * 6 + 5];
    float c0 = cosf(a0), s0v = sinf(a0);
    float c1 = cosf(a1), s1v = sinf(a1);
    float c2 = cosf(a2), s2v = sinf(a2);
    float R[3][3];
    R[0][0] = c0 * c1;
    R[0][1] = c0 * s1v * s2v - s0v * c2;
    R[0][2] = c0 * s1v * c2 + s0v * s2v;
    R[1][0] = s0v * c1;
    R[1][1] = s0v * s1v * s2v + c0 * c2;
    R[1][2] = s0v * s1v * c2 - c0 * s2v;
    R[2][0] = -s1v;
    R[2][1] = c1 * s2v;
    R[2][2] = c1 * c2;
    const float SZv[3] = {256.f, 256.f, 16.f};
    const float cen[3] = {128.f, 128.f, 8.f};
    const float tr[3] = {t0, t1, t2};
    float* rt = RT + (b * 4 + t) * 12;
#pragma unroll
    for (int kq = 0; kq < 3; ++kq)
#pragma unroll
      for (int s = 0; s < 3; ++s) rt[kq * 3 + s] = R[kq][s];
#pragma unroll
    for (int s = 0; s < 3; ++s)
      rt[9 + s] = tr[s] * SZv[s] + cen[s] - (128.f * R[0][s] + 128.f * R[1][s] + 8.f * R[2][s]);
  }
}

// ====== flow + grid_out + trilinear grid-sample -> X_t ======
__global__ __launch_bounds__(256) void k_flow(const float* __restrict__ x,
                                              const float* __restrict__ RT,
                                              float* __restrict__ out) {
  const int bid = blockIdx.x;
  const int b = bid >> 12;
  const int l = ((bid & 4095) << 8) | threadIdx.x;
  const int i = l >> 12, j = (l >> 4) & 255, k = l & 15;
  const float fi = (float)i, fj = (float)j, fk = (float)k;
  const float* __restrict__ rt = RT + b * 48;

  const float txs[4] = {64.f, 64.f, 192.f, 192.f};
  const float tys[4] = {64.f, 192.f, 64.f, 192.f};
  float e[4], es = 0.f;
#pragma unroll
  for (int t = 0; t < 4; ++t) {
    float dx = fi - txs[t], dy = fj - tys[t], dz = fk - 8.f;
    float d = __builtin_amdgcn_sqrtf(fmaf(dx, dx, fmaf(dy, dy, dz * dz)));
    e[t] = __expf(-0.1f * d);
    es += e[t];
  }
  float inv = __builtin_amdgcn_rcpf(es);
  float f0 = 0.f, f1 = 0.f, f2 = 0.f;
#pragma unroll
  for (int t = 0; t < 4; ++t) {
    float wt = e[t] * inv;
    const float* r = rt + t * 12;
    f0 += wt * (fi * r[0] + fj * r[3] + fk * r[6] + r[9]);
    f1 += wt * (fi * r[1] + fj * r[4] + fk * r[7] + r[10]);
    f2 += wt * (fi * r[2] + fj * r[5] + fk * r[8] + r[11]);
  }
  float nf0 = f0 * (1.f / 128.f) - 1.f;
  float nf1 = f1 * (1.f / 128.f) - 1.f;
  float nf2 = f2 * 0.125f - 1.f;

  int gbase = OUT_GRID + ((b << 20) + l) * 3;
  __builtin_nontemporal_store(nf2, &out[gbase]);
  __builtin_nontemporal_store(nf1, &out[gbase + 1]);
  __builtin_nontemporal_store(nf0, &out[gbase + 2]);

  float ix = ((nf2 + 1.f) * 16.f - 1.f) * 0.5f;
  float iy = ((nf1 + 1.f) * 256.f - 1.f) * 0.5f;
  float iz = ((nf0 + 1.f) * 256.f - 1.f) * 0.5f;
  float xf = floorf(ix), yf = floorf(iy), zf = floorf(iz);
  float fx = ix - xf, fy = iy - yf, fz = iz - zf;
  int x0 = (int)xf, y0 = (int)yf, z0 = (int)zf;
  int x1 = x0 + 1, y1 = y0 + 1, z1 = z0 + 1;
  bool vx0 = ((unsigned)x0 < 16u), vx1 = ((unsigned)x1 < 16u);
  bool vy0 = ((unsigned)y0 < 256u), vy1 = ((unsigned)y1 < 256u);
  bool vz0 = ((unsigned)z0 < 256u), vz1 = ((unsigned)z1 < 256u);
  int cx0 = min(max(x0, 0), 15), cx1 = min(max(x1, 0), 15);
  int cy0 = min(max(y0, 0), 255), cy1 = min(max(y1, 0), 255);
  int cz0 = min(max(z0, 0), 255), cz1 = min(max(z1, 0), 255);
  float wx0 = 1.f - fx, wx1 = fx, wy0 = 1.f - fy, wy1 = fy, wz0 = 1.f - fz, wz1 = fz;

  float W000 = wz0 * wy0 * wx0 * ((vz0 && vy0 && vx0) ? 1.f : 0.f);
  float W001 = wz0 * wy0 * wx1 * ((vz0 && vy0 && vx1) ? 1.f : 0.f);
  float W010 = wz0 * wy1 * wx0 * ((vz0 && vy1 && vx0) ? 1.f : 0.f);
  float W011 = wz0 * wy1 * wx1 * ((vz0 && vy1 && vx1) ? 1.f : 0.f);
  float W100 = wz1 * wy0 * wx0 * ((vz1 && vy0 && vx0) ? 1.f : 0.f);
  float W101 = wz1 * wy0 * wx1 * ((vz1 && vy0 && vx1) ? 1.f : 0.f);
  float W110 = wz1 * wy1 * wx0 * ((vz1 && vy1 && vx0) ? 1.f : 0.f);
  float W111 = wz1 * wy1 * wx1 * ((vz1 && vy1 && vx1) ? 1.f : 0.f);

  int o000 = (cz0 << 12) + (cy0 << 4) + cx0;
  int o001 = (cz0 << 12) + (cy0 << 4) + cx1;
  int o010 = (cz0 << 12) + (cy1 << 4) + cx0;
  int o011 = (cz0 << 12) + (cy1 << 4) + cx1;
  int o100 = (cz1 << 12) + (cy0 << 4) + cx0;
  int o101 = (cz1 << 12) + (cy0 << 4) + cx1;
  int o110 = (cz1 << 12) + (cy1 << 4) + cx0;
  int o111 = (cz1 << 12) + (cy1 << 4) + cx1;

#pragma unroll
  for (int c = 0; c < 4; ++c) {
    const float* __restrict__ xb = x + (((b * 4 + c) << 20));
    float v = W000 * xb[o000] + W001 * xb[o001] + W010 * xb[o010] + W011 * xb[o011] +
              W100 * xb[o100] + W101 * xb[o101] + W110 * xb[o110] + W111 * xb[o111];
    __builtin_nontemporal_store(v, &out[OUT_XT + ((b * 4 + c) << 20) + l]);
  }
}

// ====== moved + reg ======
__global__ __launch_bounds__(256) void k_tail(const float* __restrict__ P,
                                              const float* __restrict__ centers,
                                              const int* __restrict__ times,
                                              float* __restrict__ out) {
  const int b = blockIdx.x, tid = threadIdx.x;
  __shared__ float sred[256];
  float nrm = 0.f;
  if (tid < 200) {
    int tb = times[b];
    float p0 = P[tid * 96 + tb];
    float p1 = P[tid * 96 + 32 + tb];
    float p2 = P[tid * 96 + 64 + tb];
    int i0 = (int)rintf(p0), i1 = (int)rintf(p1), i2 = (int)rintf(p2);
    int lp = (i0 << 12) + (i1 << 4) + i2;
    int gb = OUT_GRID + ((b << 20) + lp) * 3;
    float a0 = out[gb + 2];
    float a1 = out[gb + 1];
    float a2 = out[gb + 0];
    float m0 = 2.f * p0 - (0.5f + 0.5f * a0) * 255.f;
    float m1 = 2.f * p1 - (0.5f + 0.5f * a1) * 255.f;
    float m2 = 2.f * p2 - (0.5f + 0.5f * a2) * 15.f;
    int mo = OUT_MOVED + (b * 200 + tid) * 3;
    out[mo] = m0;
    out[mo + 1] = m1;
    out[mo + 2] = m2;
    float d0 = m0 - centers[tid * 3];
    float d1 = m1 - centers[tid * 3 + 1];
    float d2 = m2 - centers[tid * 3 + 2];
    nrm = sqrtf(d0 * d0 + d1 * d1 + d2 * d2);
  }
  sred[tid] = nrm;
  __syncthreads();
  for (int s = 128; s > 0; s >>= 1) {
    if (tid < s) sred[tid] += sred[tid + s];
    __syncthreads();
  }
  if (tid == 0) out[OUT_REG + b] = sred[0] * 0.005f;
}

extern "C" void kernel_launch(void* const* d_in, const int* in_sizes, int n_in,
                              void* d_out, int out_size, void* d_ws, size_t ws_size,
                              hipStream_t stream) {
  const float* x = (const float*)d_in[0];
  const int* times = (const int*)d_in[1];
  const float* w1 = (const float*)d_in[2];
  const float* b1 = (const float*)d_in[3];
  const float* w2 = (const float*)d_in[4];
  const float* b2 = (const float*)d_in[5];
  const float* fw1 = (const float*)d_in[6];
  const float* fb1 = (const float*)d_in[7];
  const float* fw2 = (const float*)d_in[8];
  const float* fb2 = (const float*)d_in[9];
  const float* P = (const float*)d_in[10];
  const float* centers = (const float*)d_in[11];
  float* out = (float*)d_out;

  float* wt1 = (float*)d_ws;          // 1568 floats
  float* wt2 = wt1 + 1568;            // 2000 floats

  float* buf1 = out + WS_BUF1;
  float* buf2 = out + WS_BUF2;
  float* partial = out + WS_PART;
  float* RT = out + WS_RT;

  k_prep<<<1, 256, 0, stream>>>(w1, w2, wt1, wt2);
  k_conv1<<<dim3(32, 32, 8), 256, 0, stream>>>(x, wt1, b1, buf1);
  k_conv2<<<dim3(15, 15, 8), 256, 0, stream>>>(buf1, wt2, b2, buf2);
  k_fc1<<<2048, 256, 0, stream>>>(buf2, fw1, partial);
  k_head<<<1, 256, 0, stream>>>(partial, fb1, fw2, fb2, RT);
  k_flow<<<32768, 256, 0, stream>>>(x, RT, out);
  k_tail<<<8, 256, 0, stream>>>(P, centers, times, out);
}

// Round 6
// 608.794 us; speedup vs baseline: 1.2605x; 1.0650x over previous
//
#include <hip/hip_runtime.h>
#include <math.h>

// ---- problem constants ----
#define OUT_XT     0
#define OUT_GRID   33554432
#define OUT_REG    58720256
#define OUT_MOVED  58720264
#define FC1_K      576000

// scratch inside d_out (regions consumed before being overwritten):
#define WS_BUF1    0          // (8,8,125,125,16) -- inside X_t region
#define WS_BUF2    16000000   // (8,10,60,60,16)
#define WS_PART    20608000   // 2048 x 256
#define WS_RED     21132288   // 64 x 256  (after partial; still inside X_t region)
#define WS_RT      58720256   // 8x4x12 -- reg+moved region, overwritten by k_tail

// ======== prep: transpose weights into [ic][dd][oc] for contiguous uniform (s_load) reads ========
__global__ __launch_bounds__(256) void k_prep(const float* __restrict__ w1,
                                              const float* __restrict__ w2,
                                              float* __restrict__ wt1,
                                              float* __restrict__ wt2) {
  const int tid = threadIdx.x;
  for (int t = tid; t < 1568; t += 256) {       // wt1[(ic*49+dd)*8+oc] = w1[(oc*4+ic)*49+dd]
    int oc = t & 7, idx = t >> 3;
    int ic = idx / 49, dd = idx % 49;
    wt1[t] = w1[(oc * 4 + ic) * 49 + dd];
  }
  for (int t = tid; t < 2000; t += 256) {       // wt2[(ic*25+dd)*10+oc] = w2[(oc*8+ic)*25+dd]
    int oc = t % 10, idx = t / 10;
    int ic = idx / 25, dd = idx % 25;
    wt2[t] = w2[(oc * 8 + ic) * 25 + dd];
  }
}

// ================= conv1 (7x7x1, 4->8) + pool(2,2,1) + relu =================
// Pad PS == 2 (mod 32): wave b64 reads hit exactly 4 dwords/bank (conflict-free minimum).
#define C1_RS 16
#define C1_PS 226
__global__ __launch_bounds__(256) void k_conv1(const float* __restrict__ x,
                                               const float* __restrict__ wt1,
                                               const float* __restrict__ b1,
                                               float* __restrict__ buf1) {
  __shared__ float sIn[16 * C1_PS];
  const int tid = threadIdx.x;
  const int tx = blockIdx.x, ty = blockIdx.y, b = blockIdx.z;

  const int k = tid & 15;
  const int pix = tid >> 4;
  const int pyl = pix >> 2, pxl = pix & 3;
  const int row0 = ty * 8, col0 = tx * 8;

  float acc[2][2][8];
#pragma unroll
  for (int a = 0; a < 2; ++a)
#pragma unroll
    for (int c = 0; c < 2; ++c)
#pragma unroll
      for (int oc = 0; oc < 8; ++oc) acc[a][c][oc] = 0.f;

  const float4* __restrict__ x4 = reinterpret_cast<const float4*>(x);
#pragma unroll 1
  for (int ic = 0; ic < 4; ++ic) {
    __syncthreads();
    for (int t = tid; t < 784; t += 256) {
      int q = t & 3, pos = t >> 2;
      int coli = pos % 14, rowi = pos / 14;
      int row = row0 + rowi, col = col0 + coli;
      float4 v = make_float4(0.f, 0.f, 0.f, 0.f);
      if (row < 256 && col < 256)
        v = x4[(((b * 4 + ic) * 256 + row) * 256 + col) * 4 + q];
      int base = rowi * C1_RS + coli;
      sIn[(4 * q + 0) * C1_PS + base] = v.x;
      sIn[(4 * q + 1) * C1_PS + base] = v.y;
      sIn[(4 * q + 2) * C1_PS + base] = v.z;
      sIn[(4 * q + 3) * C1_PS + base] = v.w;
    }
    __syncthreads();
#pragma unroll 1
    for (int dy = 0; dy < 7; ++dy) {
      float v[2][8];
#pragma unroll
      for (int a = 0; a < 2; ++a) {
        const int base = k * C1_PS + (2 * pyl + a + dy) * C1_RS + 2 * pxl;
#pragma unroll
        for (int j = 0; j < 4; ++j) {
          float2 f = *reinterpret_cast<const float2*>(&sIn[base + 2 * j]);
          v[a][2 * j] = f.x;
          v[a][2 * j + 1] = f.y;
        }
      }
      const float* __restrict__ wd = wt1 + ic * 392 + dy * 56;   // uniform -> s_load
#pragma unroll
      for (int dx = 0; dx < 7; ++dx) {
#pragma unroll
        for (int a = 0; a < 2; ++a)
#pragma unroll
          for (int c = 0; c < 2; ++c) {
            const float val = v[a][c + dx];
#pragma unroll
            for (int oc = 0; oc < 8; ++oc)
              acc[a][c][oc] = fmaf(val, wd[dx * 8 + oc], acc[a][c][oc]);
          }
      }
    }
  }
  const int py = ty * 4 + pyl, px = tx * 4 + pxl;
  if (py < 125 && px < 125) {
#pragma unroll
    for (int oc = 0; oc < 8; ++oc) {
      float m = fmaxf(fmaxf(acc[0][0][oc], acc[0][1][oc]),
                      fmaxf(acc[1][0][oc], acc[1][1][oc])) + b1[oc];
      buf1[(((b * 8 + oc) * 125 + py) * 125 + px) * 16 + k] = fmaxf(m, 0.f);
    }
  }
}

// ================= conv2 (5x5x1, 8->10) + pool + relu =================
#define C2_RS 16
#define C2_PS 194
__global__ __launch_bounds__(256) void k_conv2(const float* __restrict__ in,
                                               const float* __restrict__ wt2,
                                               const float* __restrict__ b2,
                                               float* __restrict__ buf2) {
  __shared__ float sIn[16 * C2_PS];
  const int tid = threadIdx.x;
  const int tx = blockIdx.x, ty = blockIdx.y, b = blockIdx.z;

  const int k = tid & 15;
  const int pix = tid >> 4;
  const int pyl = pix >> 2, pxl = pix & 3;
  const int row0 = ty * 8, col0 = tx * 8;

  float acc[2][2][10];
#pragma unroll
  for (int a = 0; a < 2; ++a)
#pragma unroll
    for (int c = 0; c < 2; ++c)
#pragma unroll
      for (int oc = 0; oc < 10; ++oc) acc[a][c][oc] = 0.f;

  const float4* __restrict__ in4 = reinterpret_cast<const float4*>(in);
#pragma unroll 1
  for (int ic = 0; ic < 8; ++ic) {
    __syncthreads();
    for (int t = tid; t < 576; t += 256) {
      int q = t & 3, pos = t >> 2;
      int coli = pos % 12, rowi = pos / 12;
      int row = row0 + rowi, col = col0 + coli;
      float4 v = in4[(((b * 8 + ic) * 125 + row) * 125 + col) * 4 + q];
      int base = rowi * C2_RS + coli;
      sIn[(4 * q + 0) * C2_PS + base] = v.x;
      sIn[(4 * q + 1) * C2_PS + base] = v.y;
      sIn[(4 * q + 2) * C2_PS + base] = v.z;
      sIn[(4 * q + 3) * C2_PS + base] = v.w;
    }
    __syncthreads();
#pragma unroll 1
    for (int dy = 0; dy < 5; ++dy) {
      float v[2][6];
#pragma unroll
      for (int a = 0; a < 2; ++a) {
        const int base = k * C2_PS + (2 * pyl + a + dy) * C2_RS + 2 * pxl;
#pragma unroll
        for (int j = 0; j < 3; ++j) {
          float2 f = *reinterpret_cast<const float2*>(&sIn[base + 2 * j]);
          v[a][2 * j] = f.x;
          v[a][2 * j + 1] = f.y;
        }
      }
      const float* __restrict__ wd = wt2 + ic * 250 + dy * 50;   // uniform -> s_load
#pragma unroll
      for (int dx = 0; dx < 5; ++dx) {
#pragma unroll
        for (int a = 0; a < 2; ++a)
#pragma unroll
          for (int c = 0; c < 2; ++c) {
            const float val = v[a][c + dx];
#pragma unroll
            for (int oc = 0; oc < 10; ++oc)
              acc[a][c][oc] = fmaf(val, wd[dx * 10 + oc], acc[a][c][oc]);
          }
      }
    }
  }
  const int py = ty * 4 + pyl, px = tx * 4 + pxl;
#pragma unroll
  for (int oc = 0; oc < 10; ++oc) {
    float m = fmaxf(fmaxf(acc[0][0][oc], acc[0][1][oc]),
                    fmaxf(acc[1][0][oc], acc[1][1][oc])) + b2[oc];
    buf2[(((b * 10 + oc) * 60 + py) * 60 + px) * 16 + k] = fmaxf(m, 0.f);
  }
}

// ================= fc1 split-K pass 1: partial[2048][256] =================
__global__ __launch_bounds__(256) void k_fc1(const float* __restrict__ z,
                                             const float* __restrict__ w,
                                             float* __restrict__ partial) {
  const int bid = blockIdx.x, tid = threadIdx.x;
  const int b = tid >> 5, o = tid & 31;
  int k0 = bid * 282;
  int k1 = k0 + 282;
  if (k1 > FC1_K) k1 = FC1_K;
  const float* __restrict__ zp = z + b * FC1_K;
  const float* __restrict__ wp = w + o * FC1_K;
  float a0 = 0.f, a1 = 0.f, a2 = 0.f, a3 = 0.f;
  float a4 = 0.f, a5 = 0.f, a6 = 0.f, a7 = 0.f;
  int kk = k0;
  for (; kk + 8 <= k1; kk += 8) {
    a0 = fmaf(zp[kk], wp[kk], a0);
    a1 = fmaf(zp[kk + 1], wp[kk + 1], a1);
    a2 = fmaf(zp[kk + 2], wp[kk + 2], a2);
    a3 = fmaf(zp[kk + 3], wp[kk + 3], a3);
    a4 = fmaf(zp[kk + 4], wp[kk + 4], a4);
    a5 = fmaf(zp[kk + 5], wp[kk + 5], a5);
    a6 = fmaf(zp[kk + 6], wp[kk + 6], a6);
    a7 = fmaf(zp[kk + 7], wp[kk + 7], a7);
  }
  for (; kk < k1; ++kk) a0 = fmaf(zp[kk], wp[kk], a0);
  partial[bid * 256 + tid] = ((a0 + a1) + (a2 + a3)) + ((a4 + a5) + (a6 + a7));
}

// ======== red: coalesced hierarchical reduction partial[2048][256] -> red[64][256] ========
__global__ __launch_bounds__(256) void k_red(const float* __restrict__ partial,
                                             float* __restrict__ red) {
  const int bl = blockIdx.x, tid = threadIdx.x;
  const float* __restrict__ p = partial + bl * 32 * 256 + tid;
  float s0 = 0.f, s1 = 0.f, s2 = 0.f, s3 = 0.f;
#pragma unroll
  for (int i = 0; i < 32; i += 4) {
    s0 += p[i * 256];
    s1 += p[(i + 1) * 256];
    s2 += p[(i + 2) * 256];
    s3 += p[(i + 3) * 256];
  }
  red[bl * 256 + tid] = (s0 + s1) + (s2 + s3);
}

// ======== head: reduce red[64][256] -> fc1 relu -> fc2 tanh -> R, Tv ========
__global__ __launch_bounds__(256) void k_head(const float* __restrict__ red,
                                              const float* __restrict__ fc1_b,
                                              const float* __restrict__ fc2_w,
                                              const float* __restrict__ fc2_b,
                                              float* __restrict__ RT) {
  __shared__ float sH[256];
  __shared__ float sTh[8][24];
  const int tid = threadIdx.x;
  float s0 = 0.f, s1 = 0.f, s2 = 0.f, s3 = 0.f;
#pragma unroll
  for (int c = 0; c < 64; c += 4) {
    s0 += red[c * 256 + tid];
    s1 += red[(c + 1) * 256 + tid];
    s2 += red[(c + 2) * 256 + tid];
    s3 += red[(c + 3) * 256 + tid];
  }
  const int o = tid & 31;
  sH[tid] = fmaxf(((s0 + s1) + (s2 + s3)) + fc1_b[o], 0.f);
  __syncthreads();
  if (tid < 192) {
    int b = tid / 24, o2 = tid % 24;
    float a = fc2_b[o2];
#pragma unroll
    for (int i = 0; i < 32; ++i) a = fmaf(sH[b * 32 + i], fc2_w[o2 * 32 + i], a);
    sTh[b][o2] = tanhf(a);
  }
  __syncthreads();
  if (tid < 32) {
    const int b = tid >> 2, t = tid & 3;
    const float PI = 3.14159265358979323846f;
    float a0 = PI * sTh[b][t * 6 + 0];
    float a1 = PI * sTh[b][t * 6 + 1];
    float a2 = PI * sTh[b][t * 6 + 2];
    float t0 = sTh[b][t * 6 + 3], t1 = sTh[b][t * 6 + 4], t2 = sTh[b][t * 6 + 5];
    float c0 = cosf(a0), s0v = sinf(a0);
    float c1 = cosf(a1), s1v = sinf(a1);
    float c2 = cosf(a2), s2v = sinf(a2);
    float R[3][3];
    R[0][0] = c0 * c1;
    R[0][1] = c0 * s1v * s2v - s0v * c2;
    R[0][2] = c0 * s1v * c2 + s0v * s2v;
    R[1][0] = s0v * c1;
    R[1][1] = s0v * s1v * s2v + c0 * c2;
    R[1][2] = s0v * s1v * c2 - c0 * s2v;
    R[2][0] = -s1v;
    R[2][1] = c1 * s2v;
    R[2][2] = c1 * c2;
    const float SZv[3] = {256.f, 256.f, 16.f};
    const float cen[3] = {128.f, 128.f, 8.f};
    const float tr[3] = {t0, t1, t2};
    float* rt = RT + (b * 4 + t) * 12;
#pragma unroll
    for (int kq = 0; kq < 3; ++kq)
#pragma unroll
      for (int s = 0; s < 3; ++s) rt[kq * 3 + s] = R[kq][s];
#pragma unroll
    for (int s = 0; s < 3; ++s)
      rt[9 + s] = tr[s] * SZv[s] + cen[s] - (128.f * R[0][s] + 128.f * R[1][s] + 8.f * R[2][s]);
  }
}

// ====== flow + grid_out + trilinear grid-sample -> X_t ======
__global__ __launch_bounds__(256) void k_flow(const float* __restrict__ x,
                                              const float* __restrict__ RT,
                                              float* __restrict__ out) {
  const int bid = blockIdx.x;
  const int b = bid >> 12;
  const int l = ((bid & 4095) << 8) | threadIdx.x;
  const int i = l >> 12, j = (l >> 4) & 255, k = l & 15;
  const float fi = (float)i, fj = (float)j, fk = (float)k;
  const float* __restrict__ rt = RT + b * 48;

  const float txs[4] = {64.f, 64.f, 192.f, 192.f};
  const float tys[4] = {64.f, 192.f, 64.f, 192.f};
  float e[4], es = 0.f;
#pragma unroll
  for (int t = 0; t < 4; ++t) {
    float dx = fi - txs[t], dy = fj - tys[t], dz = fk - 8.f;
    float d = __builtin_amdgcn_sqrtf(fmaf(dx, dx, fmaf(dy, dy, dz * dz)));
    e[t] = __expf(-0.1f * d);
    es += e[t];
  }
  float inv = __builtin_amdgcn_rcpf(es);
  float f0 = 0.f, f1 = 0.f, f2 = 0.f;
#pragma unroll
  for (int t = 0; t < 4; ++t) {
    float wt = e[t] * inv;
    const float* r = rt + t * 12;
    f0 += wt * (fi * r[0] + fj * r[3] + fk * r[6] + r[9]);
    f1 += wt * (fi * r[1] + fj * r[4] + fk * r[7] + r[10]);
    f2 += wt * (fi * r[2] + fj * r[5] + fk * r[8] + r[11]);
  }
  float nf0 = f0 * (1.f / 128.f) - 1.f;
  float nf1 = f1 * (1.f / 128.f) - 1.f;
  float nf2 = f2 * 0.125f - 1.f;

  int gbase = OUT_GRID + ((b << 20) + l) * 3;
  __builtin_nontemporal_store(nf2, &out[gbase]);
  __builtin_nontemporal_store(nf1, &out[gbase + 1]);
  __builtin_nontemporal_store(nf0, &out[gbase + 2]);

  float ix = ((nf2 + 1.f) * 16.f - 1.f) * 0.5f;
  float iy = ((nf1 + 1.f) * 256.f - 1.f) * 0.5f;
  float iz = ((nf0 + 1.f) * 256.f - 1.f) * 0.5f;
  float xf = floorf(ix), yf = floorf(iy), zf = floorf(iz);
  float fx = ix - xf, fy = iy - yf, fz = iz - zf;
  int x0 = (int)xf, y0 = (int)yf, z0 = (int)zf;
  int x1 = x0 + 1, y1 = y0 + 1, z1 = z0 + 1;
  bool vx0 = ((unsigned)x0 < 16u), vx1 = ((unsigned)x1 < 16u);
  bool vy0 = ((unsigned)y0 < 256u), vy1 = ((unsigned)y1 < 256u);
  bool vz0 = ((unsigned)z0 < 256u), vz1 = ((unsigned)z1 < 256u);
  int cx0 = min(max(x0, 0), 15), cx1 = min(max(x1, 0), 15);
  int cy0 = min(max(y0, 0), 255), cy1 = min(max(y1, 0), 255);
  int cz0 = min(max(z0, 0), 255), cz1 = min(max(z1, 0), 255);
  float wx0 = 1.f - fx, wx1 = fx, wy0 = 1.f - fy, wy1 = fy, wz0 = 1.f - fz, wz1 = fz;

  float W000 = wz0 * wy0 * wx0 * ((vz0 && vy0 && vx0) ? 1.f : 0.f);
  float W001 = wz0 * wy0 * wx1 * ((vz0 && vy0 && vx1) ? 1.f : 0.f);
  float W010 = wz0 * wy1 * wx0 * ((vz0 && vy1 && vx0) ? 1.f : 0.f);
  float W011 = wz0 * wy1 * wx1 * ((vz0 && vy1 && vx1) ? 1.f : 0.f);
  float W100 = wz1 * wy0 * wx0 * ((vz1 && vy0 && vx0) ? 1.f : 0.f);
  float W101 = wz1 * wy0 * wx1 * ((vz1 && vy0 && vx1) ? 1.f : 0.f);
  float W110 = wz1 * wy1 * wx0 * ((vz1 && vy1 && vx0) ? 1.f : 0.f);
  float W111 = wz1 * wy1 * wx1 * ((vz1 && vy1 && vx1) ? 1.f : 0.f);

  int o000 = (cz0 << 12) + (cy0 << 4) + cx0;
  int o001 = (cz0 << 12) + (cy0 << 4) + cx1;
  int o010 = (cz0 << 12) + (cy1 << 4) + cx0;
  int o011 = (cz0 << 12) + (cy1 << 4) + cx1;
  int o100 = (cz1 << 12) + (cy0 << 4) + cx0;
  int o101 = (cz1 << 12) + (cy0 << 4) + cx1;
  int o110 = (cz1 << 12) + (cy1 << 4) + cx0;
  int o111 = (cz1 << 12) + (cy1 << 4) + cx1;

#pragma unroll
  for (int c = 0; c < 4; ++c) {
    const float* __restrict__ xb = x + (((b * 4 + c) << 20));
    float v = W000 * xb[o000] + W001 * xb[o001] + W010 * xb[o010] + W011 * xb[o011] +
              W100 * xb[o100] + W101 * xb[o101] + W110 * xb[o110] + W111 * xb[o111];
    __builtin_nontemporal_store(v, &out[OUT_XT + ((b * 4 + c) << 20) + l]);
  }
}

// ====== moved + reg ======
__global__ __launch_bounds__(256) void k_tail(const float* __restrict__ P,
                                              const float* __restrict__ centers,
                                              const int* __restrict__ times,
                                              float* __restrict__ out) {
  const int b = blockIdx.x, tid = threadIdx.x;
  __shared__ float sred[256];
  float nrm = 0.f;
  if (tid < 200) {
    int tb = times[b];
    float p0 = P[tid * 96 + tb];
    float p1 = P[tid * 96 + 32 + tb];
    float p2 = P[tid * 96 + 64 + tb];
    int i0 = (int)rintf(p0), i1 = (int)rintf(p1), i2 = (int)rintf(p2);
    int lp = (i0 << 12) + (i1 << 4) + i2;
    int gb = OUT_GRID + ((b << 20) + lp) * 3;
    float a0 = out[gb + 2];
    float a1 = out[gb + 1];
    float a2 = out[gb + 0];
    float m0 = 2.f * p0 - (0.5f + 0.5f * a0) * 255.f;
    float m1 = 2.f * p1 - (0.5f + 0.5f * a1) * 255.f;
    float m2 = 2.f * p2 - (0.5f + 0.5f * a2) * 15.f;
    int mo = OUT_MOVED + (b * 200 + tid) * 3;
    out[mo] = m0;
    out[mo + 1] = m1;
    out[mo + 2] = m2;
    float d0 = m0 - centers[tid * 3];
    float d1 = m1 - centers[tid * 3 + 1];
    float d2 = m2 - centers[tid * 3 + 2];
    nrm = sqrtf(d0 * d0 + d1 * d1 + d2 * d2);
  }
  sred[tid] = nrm;
  __syncthreads();
  for (int s = 128; s > 0; s >>= 1) {
    if (tid < s) sred[tid] += sred[tid + s];
    __syncthreads();
  }
  if (tid == 0) out[OUT_REG + b] = sred[0] * 0.005f;
}

extern "C" void kernel_launch(void* const* d_in, const int* in_sizes, int n_in,
                              void* d_out, int out_size, void* d_ws, size_t ws_size,
                              hipStream_t stream) {
  const float* x = (const float*)d_in[0];
  const int* times = (const int*)d_in[1];
  const float* w1 = (const float*)d_in[2];
  const float* b1 = (const float*)d_in[3];
  const float* w2 = (const float*)d_in[4];
  const float* b2 = (const float*)d_in[5];
  const float* fw1 = (const float*)d_in[6];
  const float* fb1 = (const float*)d_in[7];
  const float* fw2 = (const float*)d_in[8];
  const float* fb2 = (const float*)d_in[9];
  const float* P = (const float*)d_in[10];
  const float* centers = (const float*)d_in[11];
  float* out = (float*)d_out;

  float* wt1 = (float*)d_ws;          // 1568 floats
  float* wt2 = wt1 + 1568;            // 2000 floats

  float* buf1 = out + WS_BUF1;
  float* buf2 = out + WS_BUF2;
  float* partial = out + WS_PART;
  float* red = out + WS_RED;
  float* RT = out + WS_RT;

  k_prep<<<1, 256, 0, stream>>>(w1, w2, wt1, wt2);
  k_conv1<<<dim3(32, 32, 8), 256, 0, stream>>>(x, wt1, b1, buf1);
  k_conv2<<<dim3(15, 15, 8), 256, 0, stream>>>(buf1, wt2, b2, buf2);
  k_fc1<<<2048, 256, 0, stream>>>(buf2, fw1, partial);
  k_red<<<64, 256, 0, stream>>>(partial, red);
  k_head<<<1, 256, 0, stream>>>(red, fb1, fw2, fb2, RT);
  k_flow<<<32768, 256, 0, stream>>>(x, RT, out);
  k_tail<<<8, 256, 0, stream>>>(P, centers, times, out);
}

// Round 7
// 591.622 us; speedup vs baseline: 1.2971x; 1.0290x over previous
//
#include <hip/hip_runtime.h>
#include <math.h>

// ---- problem constants ----
#define OUT_XT     0
#define OUT_GRID   33554432
#define OUT_REG    58720256
#define OUT_MOVED  58720264
#define FC1_K      576000

// scratch inside d_out (regions consumed before being overwritten):
#define WS_BUF1    0          // (8,8,125,125,16) -- inside X_t region
#define WS_BUF2    16000000   // (8,10,60,60,16)
#define WS_PART    20608000   // 2000 x 256
#define WS_RED     21120000   // 80 x 256
#define WS_RT      58720256   // 8x4x12 -- reg+moved region, overwritten by k_tail

// ======== prep: transpose weights into [ic][dd][oc] for contiguous uniform (s_load) reads ========
__global__ __launch_bounds__(256) void k_prep(const float* __restrict__ w1,
                                              const float* __restrict__ w2,
                                              float* __restrict__ wt1,
                                              float* __restrict__ wt2) {
  const int tid = threadIdx.x;
  for (int t = tid; t < 1568; t += 256) {
    int oc = t & 7, idx = t >> 3;
    int ic = idx / 49, dd = idx % 49;
    wt1[t] = w1[(oc * 4 + ic) * 49 + dd];
  }
  for (int t = tid; t < 2000; t += 256) {
    int oc = t % 10, idx = t / 10;
    int ic = idx / 25, dd = idx % 25;
    wt2[t] = w2[(oc * 8 + ic) * 25 + dd];
  }
}

// ================= conv1 (7x7x1, 4->8) + pool(2,2,1) + relu =================
// T14 async-stage: global->reg issued before compute(ic), reg->LDS(other buf) after,
// one barrier per ic. Pad PS == 2 (mod 32): conflict-free b64 reads.
#define C1_RS 16
#define C1_PS 226
__global__ __launch_bounds__(256) void k_conv1(const float* __restrict__ x,
                                               const float* __restrict__ wt1,
                                               const float* __restrict__ b1,
                                               float* __restrict__ buf1) {
  __shared__ float sIn[2][16 * C1_PS];
  const int tid = threadIdx.x;
  const int tx = blockIdx.x, ty = blockIdx.y, b = blockIdx.z;

  const int k = tid & 15;
  const int pix = tid >> 4;
  const int pyl = pix >> 2, pxl = pix & 3;
  const int row0 = ty * 8, col0 = tx * 8;

  // staging geometry (constant across ic)
  int sq[4], srow[4], scol[4], sbase[4];
  bool sval[4];
#pragma unroll
  for (int it = 0; it < 4; ++it) {
    int t = tid + it * 256;
    int q = t & 3, pos = t >> 2;
    int coli = pos % 14, rowi = pos / 14;
    sq[it] = q;
    srow[it] = row0 + rowi;
    scol[it] = col0 + coli;
    sbase[it] = rowi * C1_RS + coli;
    sval[it] = (t < 784) && (srow[it] < 256) && (scol[it] < 256);
  }

  const float4* __restrict__ x4 = reinterpret_cast<const float4*>(x);
  float4 st[4];

#define C1_LOAD(ICV) do {                                                    \
  _Pragma("unroll")                                                          \
  for (int it = 0; it < 4; ++it) {                                           \
    float4 v = make_float4(0.f, 0.f, 0.f, 0.f);                              \
    if (sval[it])                                                            \
      v = x4[(((b * 4 + (ICV)) * 256 + srow[it]) * 256 + scol[it]) * 4 + sq[it]]; \
    st[it] = v;                                                              \
  } } while (0)

#define C1_WRITE(S) do {                                                     \
  _Pragma("unroll")                                                          \
  for (int it = 0; it < 4; ++it) {                                           \
    if (it < 3 || tid < 16) {                                                \
      float* sp = &sIn[S][(4 * sq[it]) * C1_PS + sbase[it]];                 \
      sp[0 * C1_PS] = st[it].x;                                              \
      sp[1 * C1_PS] = st[it].y;                                              \
      sp[2 * C1_PS] = st[it].z;                                              \
      sp[3 * C1_PS] = st[it].w;                                              \
    }                                                                        \
  } } while (0)

  float acc[2][2][8];
#pragma unroll
  for (int a = 0; a < 2; ++a)
#pragma unroll
    for (int c = 0; c < 2; ++c)
#pragma unroll
      for (int oc = 0; oc < 8; ++oc) acc[a][c][oc] = 0.f;

  C1_LOAD(0);
  C1_WRITE(0);
  __syncthreads();
  int cur = 0;

#pragma unroll 1
  for (int ic = 0; ic < 4; ++ic) {
    if (ic < 3) C1_LOAD(ic + 1);        // global latency hides under compute
    const float* __restrict__ sc = sIn[cur];
#pragma unroll 1
    for (int dy = 0; dy < 7; ++dy) {
      float v[2][8];
#pragma unroll
      for (int a = 0; a < 2; ++a) {
        const int base = k * C1_PS + (2 * pyl + a + dy) * C1_RS + 2 * pxl;
#pragma unroll
        for (int j = 0; j < 4; ++j) {
          float2 f = *reinterpret_cast<const float2*>(&sc[base + 2 * j]);
          v[a][2 * j] = f.x;
          v[a][2 * j + 1] = f.y;
        }
      }
      const float* __restrict__ wd = wt1 + ic * 392 + dy * 56;   // uniform -> s_load
#pragma unroll
      for (int dx = 0; dx < 7; ++dx) {
#pragma unroll
        for (int a = 0; a < 2; ++a)
#pragma unroll
          for (int c = 0; c < 2; ++c) {
            const float val = v[a][c + dx];
#pragma unroll
            for (int oc = 0; oc < 8; ++oc)
              acc[a][c][oc] = fmaf(val, wd[dx * 8 + oc], acc[a][c][oc]);
          }
      }
    }
    if (ic < 3) {
      C1_WRITE(cur ^ 1);                // other buffer: no hazard with readers of cur
      __syncthreads();
      cur ^= 1;
    }
  }
#undef C1_LOAD
#undef C1_WRITE

  const int py = ty * 4 + pyl, px = tx * 4 + pxl;
  if (py < 125 && px < 125) {
#pragma unroll
    for (int oc = 0; oc < 8; ++oc) {
      float m = fmaxf(fmaxf(acc[0][0][oc], acc[0][1][oc]),
                      fmaxf(acc[1][0][oc], acc[1][1][oc])) + b1[oc];
      buf1[(((b * 8 + oc) * 125 + py) * 125 + px) * 16 + k] = fmaxf(m, 0.f);
    }
  }
}

// ================= conv2 (5x5x1, 8->10) + pool + relu =================
#define C2_RS 16
#define C2_PS 194
__global__ __launch_bounds__(256) void k_conv2(const float* __restrict__ in,
                                               const float* __restrict__ wt2,
                                               const float* __restrict__ b2,
                                               float* __restrict__ buf2) {
  __shared__ float sIn[2][16 * C2_PS];
  const int tid = threadIdx.x;
  const int tx = blockIdx.x, ty = blockIdx.y, b = blockIdx.z;

  const int k = tid & 15;
  const int pix = tid >> 4;
  const int pyl = pix >> 2, pxl = pix & 3;
  const int row0 = ty * 8, col0 = tx * 8;

  int sq[3], srow[3], scol[3], sbase[3];
#pragma unroll
  for (int it = 0; it < 3; ++it) {
    int t = tid + it * 256;
    int q = t & 3, pos = t >> 2;
    int coli = pos % 12, rowi = pos / 12;
    sq[it] = q;
    srow[it] = row0 + rowi;
    scol[it] = col0 + coli;
    sbase[it] = rowi * C2_RS + coli;
  }

  const float4* __restrict__ in4 = reinterpret_cast<const float4*>(in);
  float4 st[3];

#define C2_LOAD(ICV) do {                                                    \
  _Pragma("unroll")                                                          \
  for (int it = 0; it < 3; ++it) {                                           \
    if (it < 2 || tid < 64)                                                  \
      st[it] = in4[(((b * 8 + (ICV)) * 125 + srow[it]) * 125 + scol[it]) * 4 + sq[it]]; \
  } } while (0)

#define C2_WRITE(S) do {                                                     \
  _Pragma("unroll")                                                          \
  for (int it = 0; it < 3; ++it) {                                           \
    if (it < 2 || tid < 64) {                                                \
      float* sp = &sIn[S][(4 * sq[it]) * C2_PS + sbase[it]];                 \
      sp[0 * C2_PS] = st[it].x;                                              \
      sp[1 * C2_PS] = st[it].y;                                              \
      sp[2 * C2_PS] = st[it].z;                                              \
      sp[3 * C2_PS] = st[it].w;                                              \
    }                                                                        \
  } } while (0)

  float acc[2][2][10];
#pragma unroll
  for (int a = 0; a < 2; ++a)
#pragma unroll
    for (int c = 0; c < 2; ++c)
#pragma unroll
      for (int oc = 0; oc < 10; ++oc) acc[a][c][oc] = 0.f;

  C2_LOAD(0);
  C2_WRITE(0);
  __syncthreads();
  int cur = 0;

#pragma unroll 1
  for (int ic = 0; ic < 8; ++ic) {
    if (ic < 7) C2_LOAD(ic + 1);
    const float* __restrict__ sc = sIn[cur];
#pragma unroll 1
    for (int dy = 0; dy < 5; ++dy) {
      float v[2][6];
#pragma unroll
      for (int a = 0; a < 2; ++a) {
        const int base = k * C2_PS + (2 * pyl + a + dy) * C2_RS + 2 * pxl;
#pragma unroll
        for (int j = 0; j < 3; ++j) {
          float2 f = *reinterpret_cast<const float2*>(&sc[base + 2 * j]);
          v[a][2 * j] = f.x;
          v[a][2 * j + 1] = f.y;
        }
      }
      const float* __restrict__ wd = wt2 + ic * 250 + dy * 50;   // uniform -> s_load
#pragma unroll
      for (int dx = 0; dx < 5; ++dx) {
#pragma unroll
        for (int a = 0; a < 2; ++a)
#pragma unroll
          for (int c = 0; c < 2; ++c) {
            const float val = v[a][c + dx];
#pragma unroll
            for (int oc = 0; oc < 10; ++oc)
              acc[a][c][oc] = fmaf(val, wd[dx * 10 + oc], acc[a][c][oc]);
          }
      }
    }
    if (ic < 7) {
      C2_WRITE(cur ^ 1);
      __syncthreads();
      cur ^= 1;
    }
  }
#undef C2_LOAD
#undef C2_WRITE

  const int py = ty * 4 + pyl, px = tx * 4 + pxl;
#pragma unroll
  for (int oc = 0; oc < 10; ++oc) {
    float m = fmaxf(fmaxf(acc[0][0][oc], acc[0][1][oc]),
                    fmaxf(acc[1][0][oc], acc[1][1][oc])) + b2[oc];
    buf2[(((b * 10 + oc) * 60 + py) * 60 + px) * 16 + k] = fmaxf(m, 0.f);
  }
}

// ================= fc1 split-K pass 1: partial[2000][256], float4 loads =================
__global__ __launch_bounds__(256) void k_fc1(const float* __restrict__ z,
                                             const float* __restrict__ w,
                                             float* __restrict__ partial) {
  const int bid = blockIdx.x, tid = threadIdx.x;
  const int b = tid >> 5, o = tid & 31;
  const int k0 = bid * 288;                 // 2000 * 288 == 576000, 16B-aligned
  const float4* __restrict__ zp = reinterpret_cast<const float4*>(z + b * FC1_K + k0);
  const float4* __restrict__ wp = reinterpret_cast<const float4*>(w + o * FC1_K + k0);
  float a0 = 0.f, a1 = 0.f, a2 = 0.f, a3 = 0.f;
  float a4 = 0.f, a5 = 0.f, a6 = 0.f, a7 = 0.f;
#pragma unroll 2
  for (int i = 0; i < 72; i += 2) {
    float4 z0 = zp[i], w0 = wp[i];
    float4 z1 = zp[i + 1], w1 = wp[i + 1];
    a0 = fmaf(z0.x, w0.x, a0);
    a1 = fmaf(z0.y, w0.y, a1);
    a2 = fmaf(z0.z, w0.z, a2);
    a3 = fmaf(z0.w, w0.w, a3);
    a4 = fmaf(z1.x, w1.x, a4);
    a5 = fmaf(z1.y, w1.y, a5);
    a6 = fmaf(z1.z, w1.z, a6);
    a7 = fmaf(z1.w, w1.w, a7);
  }
  partial[bid * 256 + tid] = ((a0 + a1) + (a2 + a3)) + ((a4 + a5) + (a6 + a7));
}

// ======== red: partial[2000][256] -> red[80][256] (25 rows per block, coalesced) ========
__global__ __launch_bounds__(256) void k_red(const float* __restrict__ partial,
                                             float* __restrict__ red) {
  const int bl = blockIdx.x, tid = threadIdx.x;
  const float* __restrict__ p = partial + bl * 25 * 256 + tid;
  float s0 = 0.f, s1 = 0.f, s2 = 0.f, s3 = 0.f, s4 = 0.f;
#pragma unroll
  for (int i = 0; i < 25; i += 5) {
    s0 += p[i * 256];
    s1 += p[(i + 1) * 256];
    s2 += p[(i + 2) * 256];
    s3 += p[(i + 3) * 256];
    s4 += p[(i + 4) * 256];
  }
  red[bl * 256 + tid] = ((s0 + s1) + (s2 + s3)) + s4;
}

// ======== head: reduce red[80][256] -> fc1 relu -> fc2 tanh -> R, Tv ========
__global__ __launch_bounds__(256) void k_head(const float* __restrict__ red,
                                              const float* __restrict__ fc1_b,
                                              const float* __restrict__ fc2_w,
                                              const float* __restrict__ fc2_b,
                                              float* __restrict__ RT) {
  __shared__ float sH[256];
  __shared__ float sTh[8][24];
  const int tid = threadIdx.x;
  float s0 = 0.f, s1 = 0.f, s2 = 0.f, s3 = 0.f;
#pragma unroll
  for (int c = 0; c < 80; c += 4) {
    s0 += red[c * 256 + tid];
    s1 += red[(c + 1) * 256 + tid];
    s2 += red[(c + 2) * 256 + tid];
    s3 += red[(c + 3) * 256 + tid];
  }
  const int o = tid & 31;
  sH[tid] = fmaxf(((s0 + s1) + (s2 + s3)) + fc1_b[o], 0.f);
  __syncthreads();
  if (tid < 192) {
    int b = tid / 24, o2 = tid % 24;
    float a = fc2_b[o2];
#pragma unroll
    for (int i = 0; i < 32; ++i) a = fmaf(sH[b * 32 + i], fc2_w[o2 * 32 + i], a);
    sTh[b][o2] = tanhf(a);
  }
  __syncthreads();
  if (tid < 32) {
    const int b = tid >> 2, t = tid & 3;
    const float PI = 3.14159265358979323846f;
    float a0 = PI * sTh[b][t * 6 + 0];
    float a1 = PI * sTh[b][t * 6 + 1];
    float a2 = PI * sTh[b][t * 6 + 2];
    float t0 = sTh[b][t * 6 + 3], t1 = sTh[b][t * 6 + 4], t2 = sTh[b][t * 6 + 5];
    float c0 = cosf(a0), s0v = sinf(a0);
    float c1 = cosf(a1), s1v = sinf(a1);
    float c2 = cosf(a2), s2v = sinf(a2);
    float R[3][3];
    R[0][0] = c0 * c1;
    R[0][1] = c0 * s1v * s2v - s0v * c2;
    R[0][2] = c0 * s1v * c2 + s0v * s2v;
    R[1][0] = s0v * c1;
    R[1][1] = s0v * s1v * s2v + c0 * c2;
    R[1][2] = s0v * s1v * c2 - c0 * s2v;
    R[2][0] = -s1v;
    R[2][1] = c1 * s2v;
    R[2][2] = c1 * c2;
    const float SZv[3] = {256.f, 256.f, 16.f};
    const float cen[3] = {128.f, 128.f, 8.f};
    const float tr[3] = {t0, t1, t2};
    float* rt = RT + (b * 4 + t) * 12;
#pragma unroll
    for (int kq = 0; kq < 3; ++kq)
#pragma unroll
      for (int s = 0; s < 3; ++s) rt[kq * 3 + s] = R[kq][s];
#pragma unroll
    for (int s = 0; s < 3; ++s)
      rt[9 + s] = tr[s] * SZv[s] + cen[s] - (128.f * R[0][s] + 128.f * R[1][s] + 8.f * R[2][s]);
  }
}

// ====== flow + grid_out + trilinear grid-sample -> X_t ======
__global__ __launch_bounds__(256) void k_flow(const float* __restrict__ x,
                                              const float* __restrict__ RT,
                                              float* __restrict__ out) {
  const int bid = blockIdx.x;
  const int b = bid >> 12;
  const int l = ((bid & 4095) << 8) | threadIdx.x;
  const int i = l >> 12, j = (l >> 4) & 255, k = l & 15;
  const float fi = (float)i, fj = (float)j, fk = (float)k;
  const float* __restrict__ rt = RT + b * 48;

  const float txs[4] = {64.f, 64.f, 192.f, 192.f};
  const float tys[4] = {64.f, 192.f, 64.f, 192.f};
  float e[4], es = 0.f;
#pragma unroll
  for (int t = 0; t < 4; ++t) {
    float dx = fi - txs[t], dy = fj - tys[t], dz = fk - 8.f;
    float d = __builtin_amdgcn_sqrtf(fmaf(dx, dx, fmaf(dy, dy, dz * dz)));
    e[t] = __expf(-0.1f * d);
    es += e[t];
  }
  float inv = __builtin_amdgcn_rcpf(es);
  float f0 = 0.f, f1 = 0.f, f2 = 0.f;
#pragma unroll
  for (int t = 0; t < 4; ++t) {
    float wt = e[t] * inv;
    const float* r = rt + t * 12;
    f0 += wt * (fi * r[0] + fj * r[3] + fk * r[6] + r[9]);
    f1 += wt * (fi * r[1] + fj * r[4] + fk * r[7] + r[10]);
    f2 += wt * (fi * r[2] + fj * r[5] + fk * r[8] + r[11]);
  }
  float nf0 = f0 * (1.f / 128.f) - 1.f;
  float nf1 = f1 * (1.f / 128.f) - 1.f;
  float nf2 = f2 * 0.125f - 1.f;

  int gbase = OUT_GRID + ((b << 20) + l) * 3;
  __builtin_nontemporal_store(nf2, &out[gbase]);
  __builtin_nontemporal_store(nf1, &out[gbase + 1]);
  __builtin_nontemporal_store(nf0, &out[gbase + 2]);

  float ix = ((nf2 + 1.f) * 16.f - 1.f) * 0.5f;
  float iy = ((nf1 + 1.f) * 256.f - 1.f) * 0.5f;
  float iz = ((nf0 + 1.f) * 256.f - 1.f) * 0.5f;
  float xf = floorf(ix), yf = floorf(iy), zf = floorf(iz);
  float fx = ix - xf, fy = iy - yf, fz = iz - zf;
  int x0 = (int)xf, y0 = (int)yf, z0 = (int)zf;
  int x1 = x0 + 1, y1 = y0 + 1, z1 = z0 + 1;
  bool vx0 = ((unsigned)x0 < 16u), vx1 = ((unsigned)x1 < 16u);
  bool vy0 = ((unsigned)y0 < 256u), vy1 = ((unsigned)y1 < 256u);
  bool vz0 = ((unsigned)z0 < 256u), vz1 = ((unsigned)z1 < 256u);
  int cx0 = min(max(x0, 0), 15), cx1 = min(max(x1, 0), 15);
  int cy0 = min(max(y0, 0), 255), cy1 = min(max(y1, 0), 255);
  int cz0 = min(max(z0, 0), 255), cz1 = min(max(z1, 0), 255);
  float wx0 = 1.f - fx, wx1 = fx, wy0 = 1.f - fy, wy1 = fy, wz0 = 1.f - fz, wz1 = fz;

  float W000 = wz0 * wy0 * wx0 * ((vz0 && vy0 && vx0) ? 1.f : 0.f);
  float W001 = wz0 * wy0 * wx1 * ((vz0 && vy0 && vx1) ? 1.f : 0.f);
  float W010 = wz0 * wy1 * wx0 * ((vz0 && vy1 && vx0) ? 1.f : 0.f);
  float W011 = wz0 * wy1 * wx1 * ((vz0 && vy1 && vx1) ? 1.f : 0.f);
  float W100 = wz1 * wy0 * wx0 * ((vz1 && vy0 && vx0) ? 1.f : 0.f);
  float W101 = wz1 * wy0 * wx1 * ((vz1 && vy0 && vx1) ? 1.f : 0.f);
  float W110 = wz1 * wy1 * wx0 * ((vz1 && vy1 && vx0) ? 1.f : 0.f);
  float W111 = wz1 * wy1 * wx1 * ((vz1 && vy1 && vx1) ? 1.f : 0.f);

  int o000 = (cz0 << 12) + (cy0 << 4) + cx0;
  int o001 = (cz0 << 12) + (cy0 << 4) + cx1;
  int o010 = (cz0 << 12) + (cy1 << 4) + cx0;
  int o011 = (cz0 << 12) + (cy1 << 4) + cx1;
  int o100 = (cz1 << 12) + (cy0 << 4) + cx0;
  int o101 = (cz1 << 12) + (cy0 << 4) + cx1;
  int o110 = (cz1 << 12) + (cy1 << 4) + cx0;
  int o111 = (cz1 << 12) + (cy1 << 4) + cx1;

#pragma unroll
  for (int c = 0; c < 4; ++c) {
    const float* __restrict__ xb = x + (((b * 4 + c) << 20));
    float v = W000 * xb[o000] + W001 * xb[o001] + W010 * xb[o010] + W011 * xb[o011] +
              W100 * xb[o100] + W101 * xb[o101] + W110 * xb[o110] + W111 * xb[o111];
    __builtin_nontemporal_store(v, &out[OUT_XT + ((b * 4 + c) << 20) + l]);
  }
}

// ====== moved + reg ======
__global__ __launch_bounds__(256) void k_tail(const float* __restrict__ P,
                                              const float* __restrict__ centers,
                                              const int* __restrict__ times,
                                              float* __restrict__ out) {
  const int b = blockIdx.x, tid = threadIdx.x;
  __shared__ float sred[256];
  float nrm = 0.f;
  if (tid < 200) {
    int tb = times[b];
    float p0 = P[tid * 96 + tb];
    float p1 = P[tid * 96 + 32 + tb];
    float p2 = P[tid * 96 + 64 + tb];
    int i0 = (int)rintf(p0), i1 = (int)rintf(p1), i2 = (int)rintf(p2);
    int lp = (i0 << 12) + (i1 << 4) + i2;
    int gb = OUT_GRID + ((b << 20) + lp) * 3;
    float a0 = out[gb + 2];
    float a1 = out[gb + 1];
    float a2 = out[gb + 0];
    float m0 = 2.f * p0 - (0.5f + 0.5f * a0) * 255.f;
    float m1 = 2.f * p1 - (0.5f + 0.5f * a1) * 255.f;
    float m2 = 2.f * p2 - (0.5f + 0.5f * a2) * 15.f;
    int mo = OUT_MOVED + (b * 200 + tid) * 3;
    out[mo] = m0;
    out[mo + 1] = m1;
    out[mo + 2] = m2;
    float d0 = m0 - centers[tid * 3];
    float d1 = m1 - centers[tid * 3 + 1];
    float d2 = m2 - centers[tid * 3 + 2];
    nrm = sqrtf(d0 * d0 + d1 * d1 + d2 * d2);
  }
  sred[tid] = nrm;
  __syncthreads();
  for (int s = 128; s > 0; s >>= 1) {
    if (tid < s) sred[tid] += sred[tid + s];
    __syncthreads();
  }
  if (tid == 0) out[OUT_REG + b] = sred[0] * 0.005f;
}

extern "C" void kernel_launch(void* const* d_in, const int* in_sizes, int n_in,
                              void* d_out, int out_size, void* d_ws, size_t ws_size,
                              hipStream_t stream) {
  const float* x = (const float*)d_in[0];
  const int* times = (const int*)d_in[1];
  const float* w1 = (const float*)d_in[2];
  const float* b1 = (const float*)d_in[3];
  const float* w2 = (const float*)d_in[4];
  const float* b2 = (const float*)d_in[5];
  const float* fw1 = (const float*)d_in[6];
  const float* fb1 = (const float*)d_in[7];
  const float* fw2 = (const float*)d_in[8];
  const float* fb2 = (const float*)d_in[9];
  const float* P = (const float*)d_in[10];
  const float* centers = (const float*)d_in[11];
  float* out = (float*)d_out;

  float* wt1 = (float*)d_ws;          // 1568 floats
  float* wt2 = wt1 + 1568;            // 2000 floats

  float* buf1 = out + WS_BUF1;
  float* buf2 = out + WS_BUF2;
  float* partial = out + WS_PART;
  float* red = out + WS_RED;
  float* RT = out + WS_RT;

  k_prep<<<1, 256, 0, stream>>>(w1, w2, wt1, wt2);
  k_conv1<<<dim3(32, 32, 8), 256, 0, stream>>>(x, wt1, b1, buf1);
  k_conv2<<<dim3(15, 15, 8), 256, 0, stream>>>(buf1, wt2, b2, buf2);
  k_fc1<<<2000, 256, 0, stream>>>(buf2, fw1, partial);
  k_red<<<80, 256, 0, stream>>>(partial, red);
  k_head<<<1, 256, 0, stream>>>(red, fb1, fw2, fb2, RT);
  k_flow<<<32768, 256, 0, stream>>>(x, RT, out);
  k_tail<<<8, 256, 0, stream>>>(P, centers, times, out);
}